// Round 11
// baseline (15846.255 us; speedup 1.0000x reference)
//
#include <hip/hip_runtime.h>

// ================= problem constants =================
#define TT 2048
#define NTHR 512
#define NWG 64           // 32 L0 WGs + 32 L1 WGs; 8 h-dims x 64 batches each

// ================= workspace layout (bytes) =================
#define ABORT_O 0
#define FL_O    256      // u32[64] PACKED flags (2 cache lines)
#define H0_O    16384    // 2 parity x 64KB: f32 h, granule16B = dims[4G..4G+4) x batch b
#define H1_O    (16384 + 2*65536)
#define WS_TOTAL (16384 + 4*65536)

// ================= LDS layout (byte offsets into dynamic smem) =================
// weight rows INTERLEAVED: LDS row r (0..31) = gate (r&3) of local dim (r>>2)
#define A0_HI    0       // L0: Whh0 slice [kb32][row32] bf16x8 (16KB each)
#define A0_LO    16384
#define AIH_HI   0       // L1: 4 x 16KB weight blocks
#define AIH_LO   16384
#define AHH_HI   32768
#define AHH_LO   49152
#define FWL_O    65536   // [8] f32 (L1)
#define HSH_O    65600   // [8][64] f32 h-stash for FC (L1)
#define SMEM_BYTES 67648

typedef __bf16 bf16;
typedef __bf16 bf16x8 __attribute__((ext_vector_type(8)));
typedef float f32x4 __attribute__((ext_vector_type(4)));
typedef unsigned int u32;
typedef u32 u32x4 __attribute__((ext_vector_type(4)));
typedef unsigned short u16;

__device__ __forceinline__ f32x4 MFMA(bf16x8 a, bf16x8 b, f32x4 c) {
  return __builtin_amdgcn_mfma_f32_16x16x32_bf16(a, b, c, 0, 0, 0);
}
__device__ __forceinline__ float sigf(float v) { return 1.0f / (1.0f + __expf(-v)); }
__device__ __forceinline__ float tanhfast(float x) {
  float e = __expf(2.0f * x);          // inf/0 saturate correctly to +-1
  return 1.0f - 2.0f / (e + 1.0f);
}

// ---------- deep-rail (sc0 sc1 -> Infinity Cache) transport; R3/R5/R7-proven ----------
__device__ __forceinline__ u32x4 ld16d(const void* p) {
  u32x4 v;
  asm volatile("global_load_dwordx4 %0, %1, off sc0 sc1" : "=v"(v) : "v"(p));
  return v;
}
__device__ __forceinline__ void wait_all_loads() {
  asm volatile("s_waitcnt vmcnt(0)" ::: "memory");
  __builtin_amdgcn_sched_barrier(0);
}
__device__ __forceinline__ void st32_deep(u32* p, u32 v) {
  asm volatile("global_store_dword %0, %1, off sc0 sc1" :: "v"(p), "v"(v) : "memory");
}
__device__ __forceinline__ u32 ld_deep(const u32* p) {
  u32 v;
  asm volatile("global_load_dword %0, %1, off sc0 sc1\n\ts_waitcnt vmcnt(0)"
               : "=v"(v) : "v"(p) : "memory");
  return v;
}

// value-returning split helpers (no reference-binding to vector components)
__device__ __forceinline__ u32 cv_hi(u32 w0, u32 w1) {
  float f0 = __builtin_bit_cast(float, w0);
  float f1 = __builtin_bit_cast(float, w1);
  u16 h0 = __builtin_bit_cast(u16, (bf16)f0);
  u16 h1 = __builtin_bit_cast(u16, (bf16)f1);
  return (u32)h0 | ((u32)h1 << 16);
}
__device__ __forceinline__ u32 cv_lo(u32 w0, u32 w1) {
  float f0 = __builtin_bit_cast(float, w0);
  float f1 = __builtin_bit_cast(float, w1);
  float r0 = f0 - (float)((bf16)f0);
  float r1 = f1 - (float)((bf16)f1);
  u16 l0 = __builtin_bit_cast(u16, (bf16)r0);
  u16 l1 = __builtin_bit_cast(u16, (bf16)r1);
  return (u32)l0 | ((u32)l1 << 16);
}

// f32 octet (two 16B granules = dims 8k..8k+8 of one batch) -> split-bf16 MFMA fragments
__device__ __forceinline__ void mk_frags(u32x4 qa, u32x4 qb, bf16x8& bh, bf16x8& bl) {
  u32x4 ph, pl;
  ph[0] = cv_hi(qa[0], qa[1]);  pl[0] = cv_lo(qa[0], qa[1]);
  ph[1] = cv_hi(qa[2], qa[3]);  pl[1] = cv_lo(qa[2], qa[3]);
  ph[2] = cv_hi(qb[0], qb[1]);  pl[2] = cv_lo(qb[0], qb[1]);
  ph[3] = cv_hi(qb[2], qb[3]);  pl[3] = cv_lo(qb[2], qb[3]);
  bh = __builtin_bit_cast(bf16x8, ph);
  bl = __builtin_bit_cast(bf16x8, pl);
}

// bounded lockstep barrier wait (wave0): lane l polls PACKED flags[l]; abort -> bail fast.
__device__ __forceinline__ void wait_barrier(const u32* flags, u32 need, u32* abortp) {
  const int lane = threadIdx.x & 63;
  const u32* p = flags + lane;               // packed: whole wave = 2 cache lines
  int it = 0;
  for (;;) {
    u32 v = ld_deep(p);
    if (__all((int)(v >= need))) break;
    if (((++it) & 63) == 0) {
      u32 ab = ld_deep(abortp);
      if (__any((int)(ab != 0))) break;
      if (it >= (1 << 16)) { if (lane == 0) st32_deep((u32*)abortp, 1u); break; }
    }
  }
}

extern "C" __global__ __launch_bounds__(NTHR)
void lstm_persist(const float* __restrict__ x,
                  const float* __restrict__ Wih0, const float* __restrict__ Whh0,
                  const float* __restrict__ bih0, const float* __restrict__ bhh0,
                  const float* __restrict__ Wih1, const float* __restrict__ Whh1,
                  const float* __restrict__ bih1, const float* __restrict__ bhh1,
                  const float* __restrict__ fcw, const float* __restrict__ fcb,
                  float* __restrict__ out, char* __restrict__ ws)
{
  extern __shared__ char smem[];
  const int tid  = threadIdx.x;
  const int slot = blockIdx.x;         // 0..63
  const bool isL1 = slot >= 32;
  const int sl = slot & 31;            // dim-group: dims [sl*8, sl*8+8)

  u32* abortp = (u32*)(ws + ABORT_O);
  u32* flags  = (u32*)(ws + FL_O);

  const int w = tid >> 6, l = tid & 63, lr = l & 15, lk = l >> 4;
  const int rowb = (w & 1) * 16;       // output row-tile (32 rows = 8 dims x 4 gates)
  const int colb = (w >> 1) * 16;      // batch-tile
  const int b  = colb + lr;            // this lane's batch
  const int i  = (w & 1) * 4 + lk;     // this lane's local dim (0..7)
  const int gd = sl * 8 + i;           // global dim
  // f32 store slot: granule G = gd>>2, u32 index (G*64 + b)*4 + (gd&3)
  const u32 hwi = (u32)(((sl * 2 + (i >> 2)) * 64 + b) * 4 + (i & 3));

  // ---------- one-time weight staging (interleaved rows: r = 4*dim_local + gate) ----------
  if (!isL1) {
    bf16x8* Ahi = (bf16x8*)(smem + A0_HI);
    bf16x8* Alo = (bf16x8*)(smem + A0_LO);
    for (int idx = tid; idx < 1024; idx += NTHR) {   // idx = r*32 + kb, r<32
      int r = idx >> 5, kb = idx & 31;
      int grow = (r & 3) * 256 + sl * 8 + (r >> 2);
      const float* src = Whh0 + grow * 256 + kb * 8;
      bf16x8 hi, lo;
#pragma unroll
      for (int e = 0; e < 8; e++) { float v = src[e]; bf16 h = (bf16)v; hi[e] = h; lo[e] = (bf16)(v - (float)h); }
      Ahi[kb * 32 + r] = hi;  Alo[kb * 32 + r] = lo;
    }
  } else {
    bf16x8* AihH = (bf16x8*)(smem + AIH_HI);
    bf16x8* AihL = (bf16x8*)(smem + AIH_LO);
    bf16x8* AhhH = (bf16x8*)(smem + AHH_HI);
    bf16x8* AhhL = (bf16x8*)(smem + AHH_LO);
    for (int idx = tid; idx < 1024; idx += NTHR) {
      int r = idx >> 5, kb = idx & 31;
      int grow = (r & 3) * 256 + sl * 8 + (r >> 2);
      {
        const float* src = Wih1 + grow * 256 + kb * 8;
        bf16x8 hi, lo;
#pragma unroll
        for (int e = 0; e < 8; e++) { float v = src[e]; bf16 h = (bf16)v; hi[e] = h; lo[e] = (bf16)(v - (float)h); }
        AihH[kb * 32 + r] = hi;  AihL[kb * 32 + r] = lo;
      }
      {
        const float* src = Whh1 + grow * 256 + kb * 8;
        bf16x8 hi, lo;
#pragma unroll
        for (int e = 0; e < 8; e++) { float v = src[e]; bf16 h = (bf16)v; hi[e] = h; lo[e] = (bf16)(v - (float)h); }
        AhhH[kb * 32 + r] = hi;  AhhL[kb * 32 + r] = lo;
      }
    }
    if (tid < 8) ((float*)(smem + FWL_O))[tid] = fcw[sl * 8 + tid];
  }

  // per-lane gate constants in VGPRs
  float wib_r[4], bias_r[4];
#pragma unroll
  for (int g = 0; g < 4; g++) {
    if (!isL1) { wib_r[g] = Wih0[g * 256 + gd]; bias_r[g] = bih0[g * 256 + gd] + bhh0[g * 256 + gd]; }
    else       { wib_r[g] = 0.0f;               bias_r[g] = bih1[g * 256 + gd] + bhh1[g * 256 + gd]; }
  }
  float creg = 0.0f;                   // per-lane c-state (dim i, batch b)
  const float fb = fcb[0];
  __syncthreads();

  // ================= superstep loop: L0 computes h0[t], L1 computes h1[t-1] =================
  for (int t = 0; t <= TT; ++t) {
    if (t > 0) {
      if (tid < 64) wait_barrier(flags, (u32)t, abortp);
      __syncthreads();
    }

    if (!isL1) {
      if (t < TT) {
        const char* hp = ws + H0_O + (size_t)((t - 1) & 1) * 65536;   // h0[t-1], f32
        u32x4 qa[8], qb[8];
#pragma unroll
        for (int ks = 0; ks < 8; ks++) {
          int kb = ks * 4 + lk;
          qa[ks] = ld16d(hp + (size_t)((kb * 2) * 64 + b) * 16);
          qb[ks] = ld16d(hp + (size_t)((kb * 2 + 1) * 64 + b) * 16);
        }
        float xv = x[(size_t)b * TT + t];
        wait_all_loads();

        const bf16x8* Ahi = (const bf16x8*)(smem + A0_HI);
        const bf16x8* Alo = (const bf16x8*)(smem + A0_LO);
        f32x4 acc = {0.f, 0.f, 0.f, 0.f};
        if (t > 0) {
#pragma unroll
          for (int ks = 0; ks < 8; ks++) {
            bf16x8 bh, bl;
            mk_frags(qa[ks], qb[ks], bh, bl);
            bf16x8 ah = Ahi[(ks * 4 + lk) * 32 + rowb + lr];
            bf16x8 al = Alo[(ks * 4 + lk) * 32 + rowb + lr];
            acc = MFMA(ah, bh, acc);
            acc = MFMA(ah, bl, acc);
            acc = MFMA(al, bh, acc);
          }
        }
        // in-register gates: acc[r] = gate r of (dim i, batch b)
        float pi = acc[0] + wib_r[0] * xv + bias_r[0];
        float pf = acc[1] + wib_r[1] * xv + bias_r[1];
        float pg = acc[2] + wib_r[2] * xv + bias_r[2];
        float po = acc[3] + wib_r[3] * xv + bias_r[3];
        float c = sigf(pf) * creg + sigf(pi) * tanhfast(pg);
        creg = c;
        float h = sigf(po) * tanhfast(c);
        st32_deep((u32*)(ws + H0_O + (size_t)(t & 1) * 65536) + hwi,
                  __builtin_bit_cast(u32, h));
      }
    } else {
      if (t >= 1) {
        const char* h0p = ws + H0_O + (size_t)((t - 1) & 1) * 65536;  // h0[t-1]
        const char* h1p = ws + H1_O + (size_t)(t & 1) * 65536;        // h1[t-2]
        u32x4 qa0[8], qb0[8], qa1[8], qb1[8];
#pragma unroll
        for (int ks = 0; ks < 8; ks++) {
          int kb = ks * 4 + lk;
          qa0[ks] = ld16d(h0p + (size_t)((kb * 2) * 64 + b) * 16);
          qb0[ks] = ld16d(h0p + (size_t)((kb * 2 + 1) * 64 + b) * 16);
          qa1[ks] = ld16d(h1p + (size_t)((kb * 2) * 64 + b) * 16);
          qb1[ks] = ld16d(h1p + (size_t)((kb * 2 + 1) * 64 + b) * 16);
        }
        wait_all_loads();

        const bf16x8* AihH = (const bf16x8*)(smem + AIH_HI);
        const bf16x8* AihL = (const bf16x8*)(smem + AIH_LO);
        const bf16x8* AhhH = (const bf16x8*)(smem + AHH_HI);
        const bf16x8* AhhL = (const bf16x8*)(smem + AHH_LO);
        f32x4 acc = {0.f, 0.f, 0.f, 0.f};
#pragma unroll
        for (int ks = 0; ks < 8; ks++) {
          int kb = ks * 4 + lk;
          bf16x8 bh, bl;
          mk_frags(qa0[ks], qb0[ks], bh, bl);
          bf16x8 aih = AihH[kb * 32 + rowb + lr];
          bf16x8 ail = AihL[kb * 32 + rowb + lr];
          acc = MFMA(aih, bh, acc);
          acc = MFMA(aih, bl, acc);
          acc = MFMA(ail, bh, acc);
          if (t >= 2) {
            bf16x8 ch, cl;
            mk_frags(qa1[ks], qb1[ks], ch, cl);
            bf16x8 ahh = AhhH[kb * 32 + rowb + lr];
            bf16x8 ahl = AhhL[kb * 32 + rowb + lr];
            acc = MFMA(ahh, ch, acc);
            acc = MFMA(ahh, cl, acc);
            acc = MFMA(ahl, ch, acc);
          }
        }
        float pi = acc[0] + bias_r[0];
        float pf = acc[1] + bias_r[1];
        float pg = acc[2] + bias_r[2];
        float po = acc[3] + bias_r[3];
        float c = sigf(pf) * creg + sigf(pi) * tanhfast(pg);
        creg = c;
        float h = sigf(po) * tanhfast(c);
        st32_deep((u32*)(ws + H1_O + (size_t)((t - 1) & 1) * 65536) + hwi,
                  __builtin_bit_cast(u32, h));
        ((float*)(smem + HSH_O))[i * 64 + b] = h;    // stash for inlined FC
      }
    }

    // drain deep stores, then post flag (single lockstep barrier value t+1)
    asm volatile("s_waitcnt vmcnt(0)" ::: "memory");
    __syncthreads();
    if (tid == 0 && t < TT)
      st32_deep(&flags[slot], (u32)(t + 1));

    // inlined FC on wave1 (off the polling wave, off the critical path)
    if (isL1 && t >= 1 && tid >= 64 && tid < 128) {
      const float* hsh = (const float*)(smem + HSH_O);
      const float* fwl = (const float*)(smem + FWL_O);
      int bb = tid - 64;
      float acc = 0.0f;
#pragma unroll
      for (int d = 0; d < 8; d++) acc += fwl[d] * hsh[d * 64 + bb];
      if (sl == 0) acc += fb;
      atomicAdd(out + (size_t)bb * TT + (t - 1), acc);
    }
  }
}

extern "C" void kernel_launch(void* const* d_in, const int* in_sizes, int n_in,
                              void* d_out, int out_size, void* d_ws, size_t ws_size,
                              hipStream_t stream) {
  (void)in_sizes; (void)n_in; (void)ws_size;
  (void)hipFuncSetAttribute((const void*)lstm_persist,
                            hipFuncAttributeMaxDynamicSharedMemorySize, SMEM_BYTES);
  (void)hipMemsetAsync(d_ws, 0, WS_TOTAL, stream);                           // flags + zero h-state
  (void)hipMemsetAsync(d_out, 0, (size_t)out_size * sizeof(float), stream);  // FC accumulates
  lstm_persist<<<dim3(NWG), dim3(NTHR), SMEM_BYTES, stream>>>(
      (const float*)d_in[0],
      (const float*)d_in[1], (const float*)d_in[2],
      (const float*)d_in[3], (const float*)d_in[4],
      (const float*)d_in[5], (const float*)d_in[6],
      (const float*)d_in[7], (const float*)d_in[8],
      (const float*)d_in[9], (const float*)d_in[10],
      (float*)d_out, (char*)d_ws);
}

// Round 12
// 9296.457 us; speedup vs baseline: 1.7045x; 1.7045x over previous
//
#include <hip/hip_runtime.h>

// ================= problem constants =================
#define TT 2048
#define NTHR 512
#define NWG 64           // 32 L0 WGs + 32 L1 WGs; 8 h-dims x 64 batches each

// ================= workspace layout (bytes) =================
#define ABORT_O 0
#define FL_O    1024     // 64 x 128B flags (padded; R7-proven)
#define H0_O    16384    // 4-deep ring x 64KB: hi[32kb x 64b x 8d] bf16 (32KB) + lo (32KB)
#define H1_O    (16384 + 4*65536)
#define WS_TOTAL (16384 + 4*65536 + 2*65536)

// ================= LDS layout (byte offsets into dynamic smem) =================
// weight rows INTERLEAVED: LDS row r (0..31) = gate (r&3) of local dim (r>>2)
#define A0_HI    0       // L0: Whh0 slice [kb32][row32] bf16x8 (16KB each)
#define A0_LO    16384
#define AIH_HI   0       // L1: 4 x 16KB weight blocks
#define AIH_LO   16384
#define AHH_HI   32768
#define AHH_LO   49152
#define FWL_O    65536   // [8] f32 (L1)
#define HSH_O    65600   // [8][64] f32 h-stash for FC (L1)
#define SMEM_BYTES 67648

typedef __bf16 bf16;
typedef __bf16 bf16x8 __attribute__((ext_vector_type(8)));
typedef float f32x4 __attribute__((ext_vector_type(4)));
typedef unsigned int u32;
typedef u32 u32x4 __attribute__((ext_vector_type(4)));
typedef unsigned short u16;

__device__ __forceinline__ f32x4 MFMA(bf16x8 a, bf16x8 b, f32x4 c) {
  return __builtin_amdgcn_mfma_f32_16x16x32_bf16(a, b, c, 0, 0, 0);
}
__device__ __forceinline__ float sigf(float v) { return 1.0f / (1.0f + __expf(-v)); }
__device__ __forceinline__ float tanhfast(float x) {
  float e = __expf(2.0f * x);          // inf/0 saturate correctly to +-1
  return 1.0f - 2.0f / (e + 1.0f);
}
__device__ __forceinline__ u16 bfbits(float f) { return __builtin_bit_cast(u16, (bf16)f); }

// ---------- deep-rail (sc0 sc1 -> Infinity Cache) transport; R3/R5/R7-proven ----------
__device__ __forceinline__ bf16x8 ld16d(const void* p) {
  u32x4 v;
  asm volatile("global_load_dwordx4 %0, %1, off sc0 sc1" : "=v"(v) : "v"(p));
  return __builtin_bit_cast(bf16x8, v);
}
__device__ __forceinline__ void wait_all_loads() {
  asm volatile("s_waitcnt vmcnt(0)" ::: "memory");
  __builtin_amdgcn_sched_barrier(0);
}
__device__ __forceinline__ void st16d(void* p, u16 h) {
  u32 v = h;
  asm volatile("global_store_short %0, %1, off sc0 sc1" :: "v"(p), "v"(v) : "memory");
}
__device__ __forceinline__ void st32_deep(u32* p, u32 v) {
  asm volatile("global_store_dword %0, %1, off sc0 sc1" :: "v"(p), "v"(v) : "memory");
}
__device__ __forceinline__ u32 ld_deep(const u32* p) {
  u32 v;
  asm volatile("global_load_dword %0, %1, off sc0 sc1\n\ts_waitcnt vmcnt(0)"
               : "=v"(v) : "v"(p) : "memory");
  return v;
}

// bounded barrier wait with PER-LANE-GROUP thresholds:
// lane l polls flags[l]; lanes 0-31 need >= need_lo (L0 flags), 32-63 >= need_hi (L1 flags).
__device__ __forceinline__ void wait_barrier(const u32* flags, u32 need_lo, u32 need_hi,
                                             u32* abortp) {
  const int lane = threadIdx.x & 63;
  const u32 need = (lane < 32) ? need_lo : need_hi;
  const u32* p = flags + lane * 32;          // 128B-padded flag lines (R7-proven)
  int it = 0;
  for (;;) {
    u32 v = ld_deep(p);
    if (__all((int)(v >= need))) break;
    if (((++it) & 63) == 0) {
      u32 ab = ld_deep(abortp);
      if (__any((int)(ab != 0))) break;
      if (it >= (1 << 16)) { if (lane == 0) st32_deep(abortp, 1u); break; }
    }
  }
}

extern "C" __global__ __launch_bounds__(NTHR)
void lstm_persist(const float* __restrict__ x,
                  const float* __restrict__ Wih0, const float* __restrict__ Whh0,
                  const float* __restrict__ bih0, const float* __restrict__ bhh0,
                  const float* __restrict__ Wih1, const float* __restrict__ Whh1,
                  const float* __restrict__ bih1, const float* __restrict__ bhh1,
                  const float* __restrict__ fcw, const float* __restrict__ fcb,
                  float* __restrict__ out, char* __restrict__ ws)
{
  extern __shared__ char smem[];
  const int tid  = threadIdx.x;
  const int slot = blockIdx.x;         // 0..63: L0 = 0..31, L1 = 32..63
  const bool isL1 = slot >= 32;
  const int sl = slot & 31;            // dim-group: dims [sl*8, sl*8+8)

  u32* abortp = (u32*)(ws + ABORT_O);
  u32* flags  = (u32*)(ws + FL_O);

  const int w = tid >> 6, l = tid & 63, lr = l & 15, lk = l >> 4;
  const int rowb = (w & 1) * 16;       // output row-tile (32 rows = 8 dims x 4 gates)
  const int colb = (w >> 1) * 16;      // batch-tile
  const int b  = colb + lr;            // this lane's batch
  const int i  = (w & 1) * 4 + lk;     // this lane's local dim (0..7)
  const int gd = sl * 8 + i;           // global dim

  // ---------- one-time weight staging (interleaved rows: r = 4*dim_local + gate) ----------
  if (!isL1) {
    bf16x8* Ahi = (bf16x8*)(smem + A0_HI);
    bf16x8* Alo = (bf16x8*)(smem + A0_LO);
    for (int idx = tid; idx < 1024; idx += NTHR) {   // idx = r*32 + kb, r<32
      int r = idx >> 5, kb = idx & 31;
      int grow = (r & 3) * 256 + sl * 8 + (r >> 2);
      const float* src = Whh0 + grow * 256 + kb * 8;
      bf16x8 hi, lo;
#pragma unroll
      for (int e = 0; e < 8; e++) { float v = src[e]; bf16 h = (bf16)v; hi[e] = h; lo[e] = (bf16)(v - (float)h); }
      Ahi[kb * 32 + r] = hi;  Alo[kb * 32 + r] = lo;
    }
  } else {
    bf16x8* AihH = (bf16x8*)(smem + AIH_HI);
    bf16x8* AihL = (bf16x8*)(smem + AIH_LO);
    bf16x8* AhhH = (bf16x8*)(smem + AHH_HI);
    bf16x8* AhhL = (bf16x8*)(smem + AHH_LO);
    for (int idx = tid; idx < 1024; idx += NTHR) {
      int r = idx >> 5, kb = idx & 31;
      int grow = (r & 3) * 256 + sl * 8 + (r >> 2);
      {
        const float* src = Wih1 + grow * 256 + kb * 8;
        bf16x8 hi, lo;
#pragma unroll
        for (int e = 0; e < 8; e++) { float v = src[e]; bf16 h = (bf16)v; hi[e] = h; lo[e] = (bf16)(v - (float)h); }
        AihH[kb * 32 + r] = hi;  AihL[kb * 32 + r] = lo;
      }
      {
        const float* src = Whh1 + grow * 256 + kb * 8;
        bf16x8 hi, lo;
#pragma unroll
        for (int e = 0; e < 8; e++) { float v = src[e]; bf16 h = (bf16)v; hi[e] = h; lo[e] = (bf16)(v - (float)h); }
        AhhH[kb * 32 + r] = hi;  AhhL[kb * 32 + r] = lo;
      }
    }
    if (tid < 8) ((float*)(smem + FWL_O))[tid] = fcw[sl * 8 + tid];
  }

  // per-lane gate constants in VGPRs
  float wib_r[4], bias_r[4];
#pragma unroll
  for (int g = 0; g < 4; g++) {
    if (!isL1) { wib_r[g] = Wih0[g * 256 + gd]; bias_r[g] = bih0[g * 256 + gd] + bhh0[g * 256 + gd]; }
    else       { wib_r[g] = 0.0f;               bias_r[g] = bih1[g * 256 + gd] + bhh1[g * 256 + gd]; }
  }
  float creg = 0.0f;                   // per-lane c-state (dim i, batch b)
  const float fb = fcb[0];
  __syncthreads();

  // ======== superstep loop: L0 computes h0[t] (ring-4), L1 computes h1[t-1] (parity-2) ========
  // flag semantics (R7): at end of superstep s, WG posts flag s+1.
  // L0(t) waits: L0flags >= t  (h0[t-1] complete)
  //              L1flags >= t-2 (L1 superstep t-3 done -> h0[t-4] free to overwrite; ring-4)
  // L1(t) waits: L0flags >= t  (h0[t-1] ready)
  //              L1flags >= t   (h1[t-2] complete; parity-2 self-recurrence)
  for (int t = 0; t <= TT; ++t) {
    if (t > 0) {
      if (tid < 64) {
        u32 need_hi = isL1 ? (u32)t : (t >= 2 ? (u32)(t - 2) : 0u);
        wait_barrier(flags, (u32)t, need_hi, abortp);
      }
      __syncthreads();
    }

    if (!isL1) {
      if (t < TT) {
        const char* hp = ws + H0_O + (size_t)((t + 3) & 3) * 65536;   // slot (t-1)%4
        bf16x8 bh[8], bl[8];
#pragma unroll
        for (int ks = 0; ks < 8; ks++) {
          int kb = ks * 4 + lk;
          const char* p = hp + (size_t)(kb * 64 + b) * 16;
          bh[ks] = ld16d(p);
          bl[ks] = ld16d(p + 32768);
        }
        float xv = x[(size_t)b * TT + t];
        wait_all_loads();

        const bf16x8* Ahi = (const bf16x8*)(smem + A0_HI);
        const bf16x8* Alo = (const bf16x8*)(smem + A0_LO);
        f32x4 acc = {0.f, 0.f, 0.f, 0.f};
        if (t > 0) {
#pragma unroll
          for (int ks = 0; ks < 8; ks++) {
            int kb = ks * 4 + lk;
            bf16x8 ah = Ahi[kb * 32 + rowb + lr];
            bf16x8 al = Alo[kb * 32 + rowb + lr];
            acc = MFMA(ah, bh[ks], acc);
            acc = MFMA(ah, bl[ks], acc);
            acc = MFMA(al, bh[ks], acc);
          }
        }
        // in-register gates: acc[r] = gate r of (dim i, batch b)
        float pi = acc[0] + wib_r[0] * xv + bias_r[0];
        float pf = acc[1] + wib_r[1] * xv + bias_r[1];
        float pg = acc[2] + wib_r[2] * xv + bias_r[2];
        float po = acc[3] + wib_r[3] * xv + bias_r[3];
        float c = sigf(pf) * creg + sigf(pi) * tanhfast(pg);
        creg = c;
        float h = sigf(po) * tanhfast(c);
        u16 hb = bfbits(h);
        u16 lb = bfbits(h - (float)(bf16)h);
        char* wp = ws + H0_O + (size_t)(t & 3) * 65536 + (size_t)(sl * 64 + b) * 16 + i * 2;
        st16d(wp, hb);
        st16d(wp + 32768, lb);
      }
    } else {
      if (t >= 1) {
        const char* h0p = ws + H0_O + (size_t)((t + 3) & 3) * 65536;  // h0[t-1], slot (t-1)%4
        const char* h1p = ws + H1_O + (size_t)(t & 1) * 65536;        // h1[t-2], parity
        bf16x8 b0h[8], b0l[8], b1h[8], b1l[8];
#pragma unroll
        for (int ks = 0; ks < 8; ks++) {
          int kb = ks * 4 + lk;
          const char* p0 = h0p + (size_t)(kb * 64 + b) * 16;
          const char* p1 = h1p + (size_t)(kb * 64 + b) * 16;
          b0h[ks] = ld16d(p0);  b0l[ks] = ld16d(p0 + 32768);
          b1h[ks] = ld16d(p1);  b1l[ks] = ld16d(p1 + 32768);
        }
        wait_all_loads();

        const bf16x8* AihH = (const bf16x8*)(smem + AIH_HI);
        const bf16x8* AihL = (const bf16x8*)(smem + AIH_LO);
        const bf16x8* AhhH = (const bf16x8*)(smem + AHH_HI);
        const bf16x8* AhhL = (const bf16x8*)(smem + AHH_LO);
        f32x4 acc = {0.f, 0.f, 0.f, 0.f};
#pragma unroll
        for (int ks = 0; ks < 8; ks++) {
          int kb = ks * 4 + lk;
          bf16x8 aih = AihH[kb * 32 + rowb + lr];
          bf16x8 ail = AihL[kb * 32 + rowb + lr];
          acc = MFMA(aih, b0h[ks], acc);
          acc = MFMA(aih, b0l[ks], acc);
          acc = MFMA(ail, b0h[ks], acc);
          if (t >= 2) {
            bf16x8 ahh = AhhH[kb * 32 + rowb + lr];
            bf16x8 ahl = AhhL[kb * 32 + rowb + lr];
            acc = MFMA(ahh, b1h[ks], acc);
            acc = MFMA(ahh, b1l[ks], acc);
            acc = MFMA(ahl, b1h[ks], acc);
          }
        }
        float pi = acc[0] + bias_r[0];
        float pf = acc[1] + bias_r[1];
        float pg = acc[2] + bias_r[2];
        float po = acc[3] + bias_r[3];
        float c = sigf(pf) * creg + sigf(pi) * tanhfast(pg);
        creg = c;
        float h = sigf(po) * tanhfast(c);
        u16 hb = bfbits(h);
        u16 lb = bfbits(h - (float)(bf16)h);
        char* wp = ws + H1_O + (size_t)((t - 1) & 1) * 65536 + (size_t)(sl * 64 + b) * 16 + i * 2;
        st16d(wp, hb);
        st16d(wp + 32768, lb);
        ((float*)(smem + HSH_O))[i * 64 + b] = h;    // stash for inlined FC
      }
    }

    // drain deep stores, then post flag (value t+1)
    asm volatile("s_waitcnt vmcnt(0)" ::: "memory");
    __syncthreads();
    if (tid == 0 && t < TT)
      st32_deep(flags + slot * 32, (u32)(t + 1));

    // inlined FC on wave1 (off the polling wave, off the critical path)
    if (isL1 && t >= 1 && tid >= 64 && tid < 128) {
      const float* hsh = (const float*)(smem + HSH_O);
      const float* fwl = (const float*)(smem + FWL_O);
      int bb = tid - 64;
      float acc = 0.0f;
#pragma unroll
      for (int d = 0; d < 8; d++) acc += fwl[d] * hsh[d * 64 + bb];
      if (sl == 0) acc += fb;
      atomicAdd(out + (size_t)bb * TT + (t - 1), acc);
    }
  }
}

extern "C" void kernel_launch(void* const* d_in, const int* in_sizes, int n_in,
                              void* d_out, int out_size, void* d_ws, size_t ws_size,
                              hipStream_t stream) {
  (void)in_sizes; (void)n_in; (void)ws_size;
  (void)hipFuncSetAttribute((const void*)lstm_persist,
                            hipFuncAttributeMaxDynamicSharedMemorySize, SMEM_BYTES);
  (void)hipMemsetAsync(d_ws, 0, WS_TOTAL, stream);                           // flags + zero h-state
  (void)hipMemsetAsync(d_out, 0, (size_t)out_size * sizeof(float), stream);  // FC accumulates
  lstm_persist<<<dim3(NWG), dim3(NTHR), SMEM_BYTES, stream>>>(
      (const float*)d_in[0],
      (const float*)d_in[1], (const float*)d_in[2],
      (const float*)d_in[3], (const float*)d_in[4],
      (const float*)d_in[5], (const float*)d_in[6],
      (const float*)d_in[7], (const float*)d_in[8],
      (const float*)d_in[9], (const float*)d_in[10],
      (float*)d_out, (char*)d_ws);
}

// Round 15
// 9042.850 us; speedup vs baseline: 1.7524x; 1.0280x over previous
//
#include <hip/hip_runtime.h>

// ================= problem constants =================
#define TT 2048
#define NTHR 512
#define NWG 64           // 32 L0 WGs + 32 L1 WGs; 8 h-dims x 64 batches each

// ================= workspace layout (bytes) =================
#define ABORT_O 0
#define FL_O    1024     // 64 x 128B flags (padded; R7/R12-proven)
#define H0_O    16384    // 4-deep ring x 64KB: hi[32kb x 64b x 8d] bf16 (32KB) + lo (32KB)
#define H1_O    (16384 + 4*65536)
#define WS_TOTAL (16384 + 4*65536 + 2*65536)

// ================= LDS layout (byte offsets into dynamic smem) =================
// weight rows INTERLEAVED: LDS row r (0..31) = gate (r&3) of local dim (r>>2)
#define A0_HI    0       // L0: Whh0 slice [kb32][row32] bf16x8 (16KB each)
#define A0_LO    16384
#define AIH_HI   0       // L1: 4 x 16KB weight blocks
#define AIH_LO   16384
#define AHH_HI   32768
#define AHH_LO   49152
#define FWL_O    65536   // [8] f32 (L1)
#define HSH_O    65600   // [8][64] f32 h-stash for FC (L1)
#define SMEM_BYTES 67648

typedef __bf16 bf16;
typedef __bf16 bf16x8 __attribute__((ext_vector_type(8)));
typedef float f32x4 __attribute__((ext_vector_type(4)));
typedef unsigned int u32;
typedef u32 u32x4 __attribute__((ext_vector_type(4)));
typedef unsigned short u16;

__device__ __forceinline__ f32x4 MFMA(bf16x8 a, bf16x8 b, f32x4 c) {
  return __builtin_amdgcn_mfma_f32_16x16x32_bf16(a, b, c, 0, 0, 0);
}
__device__ __forceinline__ float sigf(float v) { return 1.0f / (1.0f + __expf(-v)); }
__device__ __forceinline__ float tanhfast(float x) {
  float e = __expf(2.0f * x);          // inf/0 saturate correctly to +-1
  return 1.0f - 2.0f / (e + 1.0f);
}
__device__ __forceinline__ u16 bfbits(float f) { return __builtin_bit_cast(u16, (bf16)f); }

// ---------- deep-rail (sc0 sc1 -> Infinity Cache) transport; R3/R5/R7/R12-proven ----------
__device__ __forceinline__ bf16x8 ld16d(const void* p) {
  u32x4 v;
  asm volatile("global_load_dwordx4 %0, %1, off sc0 sc1" : "=v"(v) : "v"(p));
  return __builtin_bit_cast(bf16x8, v);
}
__device__ __forceinline__ void wait_all_loads() {
  asm volatile("s_waitcnt vmcnt(0)" ::: "memory");
  __builtin_amdgcn_sched_barrier(0);
}
__device__ __forceinline__ void st32_deep(u32* p, u32 v) {
  asm volatile("global_store_dword %0, %1, off sc0 sc1" :: "v"(p), "v"(v) : "memory");
}
__device__ __forceinline__ u32 ld_deep(const u32* p) {
  u32 v;
  asm volatile("global_load_dword %0, %1, off sc0 sc1\n\ts_waitcnt vmcnt(0)"
               : "=v"(v) : "v"(p) : "memory");
  return v;
}

// bounded barrier wait with PER-LANE-GROUP thresholds (R12-proven):
// lane l polls flags[l]; lanes 0-31 need >= need_lo (L0 flags), 32-63 >= need_hi (L1 flags).
__device__ __forceinline__ void wait_barrier(const u32* flags, u32 need_lo, u32 need_hi,
                                             u32* abortp) {
  const int lane = threadIdx.x & 63;
  const u32 need = (lane < 32) ? need_lo : need_hi;
  const u32* p = flags + lane * 32;          // 128B-padded flag lines
  int it = 0;
  for (;;) {
    u32 v = ld_deep(p);
    if (__all((int)(v >= need))) break;
    if (((++it) & 63) == 0) {
      u32 ab = ld_deep(abortp);
      if (__any((int)(ab != 0))) break;
      if (it >= (1 << 16)) { if (lane == 0) st32_deep(abortp, 1u); break; }
    }
  }
}

extern "C" __global__ __launch_bounds__(NTHR)
void lstm_persist(const float* __restrict__ x,
                  const float* __restrict__ Wih0, const float* __restrict__ Whh0,
                  const float* __restrict__ bih0, const float* __restrict__ bhh0,
                  const float* __restrict__ Wih1, const float* __restrict__ Whh1,
                  const float* __restrict__ bih1, const float* __restrict__ bhh1,
                  const float* __restrict__ fcw, const float* __restrict__ fcb,
                  float* __restrict__ out, char* __restrict__ ws)
{
  extern __shared__ char smem[];
  const int tid  = threadIdx.x;
  const int slot = blockIdx.x;         // 0..63: L0 = 0..31, L1 = 32..63
  const bool isL1 = slot >= 32;
  const int sl = slot & 31;            // dim-group: dims [sl*8, sl*8+8)

  u32* abortp = (u32*)(ws + ABORT_O);
  u32* flags  = (u32*)(ws + FL_O);

  const int w = tid >> 6, l = tid & 63, lr = l & 15, lk = l >> 4;
  const int rowb = (w & 1) * 16;       // output row-tile (32 rows = 8 dims x 4 gates)
  const int colb = (w >> 1) * 16;      // batch-tile
  const int b  = colb + lr;            // this lane's batch
  const int i  = (w & 1) * 4 + lk;     // this lane's local dim (0..7)
  const int gd = sl * 8 + i;           // global dim

  // ---------- one-time weight staging (interleaved rows: r = 4*dim_local + gate) ----------
  if (!isL1) {
    bf16x8* Ahi = (bf16x8*)(smem + A0_HI);
    bf16x8* Alo = (bf16x8*)(smem + A0_LO);
    for (int idx = tid; idx < 1024; idx += NTHR) {   // idx = r*32 + kb, r<32
      int r = idx >> 5, kb = idx & 31;
      int grow = (r & 3) * 256 + sl * 8 + (r >> 2);
      const float* src = Whh0 + grow * 256 + kb * 8;
      bf16x8 hi, lo;
#pragma unroll
      for (int e = 0; e < 8; e++) { float v = src[e]; bf16 h = (bf16)v; hi[e] = h; lo[e] = (bf16)(v - (float)h); }
      Ahi[kb * 32 + r] = hi;  Alo[kb * 32 + r] = lo;
    }
  } else {
    bf16x8* AihH = (bf16x8*)(smem + AIH_HI);
    bf16x8* AihL = (bf16x8*)(smem + AIH_LO);
    bf16x8* AhhH = (bf16x8*)(smem + AHH_HI);
    bf16x8* AhhL = (bf16x8*)(smem + AHH_LO);
    for (int idx = tid; idx < 1024; idx += NTHR) {
      int r = idx >> 5, kb = idx & 31;
      int grow = (r & 3) * 256 + sl * 8 + (r >> 2);
      {
        const float* src = Wih1 + grow * 256 + kb * 8;
        bf16x8 hi, lo;
#pragma unroll
        for (int e = 0; e < 8; e++) { float v = src[e]; bf16 h = (bf16)v; hi[e] = h; lo[e] = (bf16)(v - (float)h); }
        AihH[kb * 32 + r] = hi;  AihL[kb * 32 + r] = lo;
      }
      {
        const float* src = Whh1 + grow * 256 + kb * 8;
        bf16x8 hi, lo;
#pragma unroll
        for (int e = 0; e < 8; e++) { float v = src[e]; bf16 h = (bf16)v; hi[e] = h; lo[e] = (bf16)(v - (float)h); }
        AhhH[kb * 32 + r] = hi;  AhhL[kb * 32 + r] = lo;
      }
    }
    if (tid < 8) ((float*)(smem + FWL_O))[tid] = fcw[sl * 8 + tid];
  }

  // per-lane gate constants in VGPRs
  float wib_r[4], bias_r[4];
#pragma unroll
  for (int g = 0; g < 4; g++) {
    if (!isL1) { wib_r[g] = Wih0[g * 256 + gd]; bias_r[g] = bih0[g * 256 + gd] + bhh0[g * 256 + gd]; }
    else       { wib_r[g] = 0.0f;               bias_r[g] = bih1[g * 256 + gd] + bhh1[g * 256 + gd]; }
  }
  float creg = 0.0f;                   // per-lane c-state (dim i, batch b)
  const float fb = fcb[0];
  __syncthreads();

  // ======== superstep loop: L0 computes h0[t] (ring-4), L1 computes h1[t-1] (parity-2) ========
  // flag semantics (R7/R12-proven): at end of superstep s, WG posts flag s+1.
  // L0(t) waits: L0flags >= t ; L1flags >= t-2 (ring-4 overwrite guard)
  // L1(t) waits: L0flags >= t ; L1flags >= t   (h1 self-recurrence + parity guard)
  for (int t = 0; t <= TT; ++t) {
    if (t > 0) {
      if (tid < 64) {
        u32 need_hi = isL1 ? (u32)t : (t >= 2 ? (u32)(t - 2) : 0u);
        wait_barrier(flags, (u32)t, need_hi, abortp);
      }
      __syncthreads();
    }

    if (!isL1) {
      if (t < TT) {
        const char* hp = ws + H0_O + (size_t)((t + 3) & 3) * 65536;   // slot (t-1)%4
        bf16x8 bh[8], bl[8];
#pragma unroll
        for (int ks = 0; ks < 8; ks++) {
          int kb = ks * 4 + lk;
          const char* p = hp + (size_t)(kb * 64 + b) * 16;
          bh[ks] = ld16d(p);
          bl[ks] = ld16d(p + 32768);
        }
        float xv = x[(size_t)b * TT + t];
        wait_all_loads();

        const bf16x8* Ahi = (const bf16x8*)(smem + A0_HI);
        const bf16x8* Alo = (const bf16x8*)(smem + A0_LO);
        f32x4 acc = {0.f, 0.f, 0.f, 0.f};
        if (t > 0) {
#pragma unroll
          for (int ks = 0; ks < 8; ks++) {
            int kb = ks * 4 + lk;
            bf16x8 ah = Ahi[kb * 32 + rowb + lr];
            bf16x8 al = Alo[kb * 32 + rowb + lr];
            acc = MFMA(ah, bh[ks], acc);
            acc = MFMA(ah, bl[ks], acc);
            acc = MFMA(al, bh[ks], acc);
          }
        }
        // in-register gates: acc[r] = gate r of (dim i, batch b)
        float pi = acc[0] + wib_r[0] * xv + bias_r[0];
        float pf = acc[1] + wib_r[1] * xv + bias_r[1];
        float pg = acc[2] + wib_r[2] * xv + bias_r[2];
        float po = acc[3] + wib_r[3] * xv + bias_r[3];
        float c = sigf(pf) * creg + sigf(pi) * tanhfast(pg);
        creg = c;
        float h = sigf(po) * tanhfast(c);
        // packed store: lane pair (lk, lk^1) -> one dword per component from even lane
        u32 hw = (u32)bfbits(h);
        u32 lw = (u32)bfbits(h - (float)(bf16)h);
        u32 ho = (u32)__shfl_xor((int)hw, 16);
        u32 lo2 = (u32)__shfl_xor((int)lw, 16);
        if (!(lk & 1)) {
          char* wp = ws + H0_O + (size_t)(t & 3) * 65536 + (size_t)(sl * 64 + b) * 16 + i * 2;
          st32_deep((u32*)wp, hw | (ho << 16));
          st32_deep((u32*)(wp + 32768), lw | (lo2 << 16));
        }
      }
    } else {
      if (t >= 1) {
        // issue h1[t-2] loads FIRST (critical recurrence data), then h0[t-1]
        bf16x8 b0h[8], b0l[8], b1h[8], b1l[8];
        if (t >= 2) {
          const char* h1p = ws + H1_O + (size_t)(t & 1) * 65536;      // h1[t-2], parity
#pragma unroll
          for (int ks = 0; ks < 8; ks++) {
            int kb = ks * 4 + lk;
            const char* p1 = h1p + (size_t)(kb * 64 + b) * 16;
            b1h[ks] = ld16d(p1);  b1l[ks] = ld16d(p1 + 32768);
          }
        }
        {
          const char* h0p = ws + H0_O + (size_t)((t + 3) & 3) * 65536; // h0[t-1], slot (t-1)%4
#pragma unroll
          for (int ks = 0; ks < 8; ks++) {
            int kb = ks * 4 + lk;
            const char* p0 = h0p + (size_t)(kb * 64 + b) * 16;
            b0h[ks] = ld16d(p0);  b0l[ks] = ld16d(p0 + 32768);
          }
        }
        wait_all_loads();

        const bf16x8* AihH = (const bf16x8*)(smem + AIH_HI);
        const bf16x8* AihL = (const bf16x8*)(smem + AIH_LO);
        const bf16x8* AhhH = (const bf16x8*)(smem + AHH_HI);
        const bf16x8* AhhL = (const bf16x8*)(smem + AHH_LO);
        // 4 accumulator chains (ks-parity x ih/hh) to pipeline MFMA dep-latency
        f32x4 aA = {0.f,0.f,0.f,0.f}, aB = {0.f,0.f,0.f,0.f};
        f32x4 aC = {0.f,0.f,0.f,0.f}, aD = {0.f,0.f,0.f,0.f};
#pragma unroll
        for (int ks = 0; ks < 8; ks++) {
          int kb = ks * 4 + lk;
          bf16x8 aih = AihH[kb * 32 + rowb + lr];
          bf16x8 ail = AihL[kb * 32 + rowb + lr];
          if (ks & 1) { aB = MFMA(aih, b0h[ks], aB); aB = MFMA(aih, b0l[ks], aB); aB = MFMA(ail, b0h[ks], aB); }
          else        { aA = MFMA(aih, b0h[ks], aA); aA = MFMA(aih, b0l[ks], aA); aA = MFMA(ail, b0h[ks], aA); }
        }
        if (t >= 2) {
#pragma unroll
          for (int ks = 0; ks < 8; ks++) {
            int kb = ks * 4 + lk;
            bf16x8 ahh = AhhH[kb * 32 + rowb + lr];
            bf16x8 ahl = AhhL[kb * 32 + rowb + lr];
            if (ks & 1) { aD = MFMA(ahh, b1h[ks], aD); aD = MFMA(ahh, b1l[ks], aD); aD = MFMA(ahl, b1h[ks], aD); }
            else        { aC = MFMA(ahh, b1h[ks], aC); aC = MFMA(ahh, b1l[ks], aC); aC = MFMA(ahl, b1h[ks], aC); }
          }
        }
        float pi = ((aA[0] + aB[0]) + (aC[0] + aD[0])) + bias_r[0];
        float pf = ((aA[1] + aB[1]) + (aC[1] + aD[1])) + bias_r[1];
        float pg = ((aA[2] + aB[2]) + (aC[2] + aD[2])) + bias_r[2];
        float po = ((aA[3] + aB[3]) + (aC[3] + aD[3])) + bias_r[3];
        float c = sigf(pf) * creg + sigf(pi) * tanhfast(pg);
        creg = c;
        float h = sigf(po) * tanhfast(c);
        // packed store (as L0)
        u32 hw = (u32)bfbits(h);
        u32 lw = (u32)bfbits(h - (float)(bf16)h);
        u32 ho = (u32)__shfl_xor((int)hw, 16);
        u32 lo2 = (u32)__shfl_xor((int)lw, 16);
        if (!(lk & 1)) {
          char* wp = ws + H1_O + (size_t)((t - 1) & 1) * 65536 + (size_t)(sl * 64 + b) * 16 + i * 2;
          st32_deep((u32*)wp, hw | (ho << 16));
          st32_deep((u32*)(wp + 32768), lw | (lo2 << 16));
        }
        ((float*)(smem + HSH_O))[i * 64 + b] = h;    // stash for inlined FC
      }
    }

    // drain deep stores, then post flag (value t+1)
    asm volatile("s_waitcnt vmcnt(0)" ::: "memory");
    __syncthreads();
    if (tid == 0 && t < TT)
      st32_deep(flags + slot * 32, (u32)(t + 1));

    // inlined FC on wave1 (off the polling wave, off the critical path)
    if (isL1 && t >= 1 && tid >= 64 && tid < 128) {
      const float* hsh = (const float*)(smem + HSH_O);
      const float* fwl = (const float*)(smem + FWL_O);
      int bb = tid - 64;
      float acc = 0.0f;
#pragma unroll
      for (int d = 0; d < 8; d++) acc += fwl[d] * hsh[d * 64 + bb];
      if (sl == 0) acc += fb;
      atomicAdd(out + (size_t)bb * TT + (t - 1), acc);
    }
  }
}

extern "C" void kernel_launch(void* const* d_in, const int* in_sizes, int n_in,
                              void* d_out, int out_size, void* d_ws, size_t ws_size,
                              hipStream_t stream) {
  (void)in_sizes; (void)n_in; (void)ws_size;
  (void)hipFuncSetAttribute((const void*)lstm_persist,
                            hipFuncAttributeMaxDynamicSharedMemorySize, SMEM_BYTES);
  (void)hipMemsetAsync(d_ws, 0, WS_TOTAL, stream);                           // flags + zero h-state
  (void)hipMemsetAsync(d_out, 0, (size_t)out_size * sizeof(float), stream);  // FC accumulates
  lstm_persist<<<dim3(NWG), dim3(NTHR), SMEM_BYTES, stream>>>(
      (const float*)d_in[0],
      (const float*)d_in[1], (const float*)d_in[2],
      (const float*)d_in[3], (const float*)d_in[4],
      (const float*)d_in[5], (const float*)d_in[6],
      (const float*)d_in[7], (const float*)d_in[8],
      (const float*)d_in[9], (const float*)d_in[10],
      (float*)d_out, (char*)d_ws);
}